// Round 5
// baseline (1068.948 us; speedup 1.0000x reference)
//
#include <hip/hip_runtime.h>
#include <hip/hip_bf16.h>
#include <math.h>

#define N_NODES 50000
#define N_EDGES 1600000
#define IN_DIM 16
#define HID 64

typedef __attribute__((ext_vector_type(8))) short short8v;
typedef __attribute__((ext_vector_type(16))) float f32x16;

union U32x4S8 { unsigned u[4]; short8v s; };

__device__ __forceinline__ float lrelu(float v) { return v > 0.f ? v : 0.2f * v; }

__device__ __forceinline__ float wave_reduce_sum(float v) {
    #pragma unroll
    for (int off = 32; off > 0; off >>= 1) v += __shfl_down(v, off, 64);
    return v;
}

// online-softmax state update: state (m, den, acc) absorbs element (e, v)
__device__ __forceinline__ void sm_upd(float& m, float& den, float& acc, float e, float v) {
    float n = fmaxf(m, e);
    float f = __expf(m - n), w = __expf(e - n);
    den = den * f + w;
    acc = acc * f + w * v;
    m = n;
}
// associative merge of two online-softmax states
__device__ __forceinline__ void sm_merge(float& m, float& den, float& acc,
                                         float m2, float den2, float acc2) {
    float mm = fmaxf(m, m2);
    float f1 = __expf(m - mm), f2 = __expf(m2 - mm);
    den = den * f1 + den2 * f2;
    acc = acc * f1 + acc2 * f2;
    m = mm;
}

__device__ __forceinline__ unsigned pk_bf16(float a, float b) {
    unsigned ua = (unsigned)__bfloat16_as_ushort(__float2bfloat16(a));
    unsigned ub = (unsigned)__bfloat16_as_ushort(__float2bfloat16(b));
    return ua | (ub << 16);
}

__device__ __forceinline__ void hilo2(float f0, float f1, unsigned& hw, unsigned& lw) {
    __hip_bfloat16 h0 = __float2bfloat16(f0), h1 = __float2bfloat16(f1);
    float r0 = __bfloat162float(h0), r1 = __bfloat162float(h1);
    hw = (unsigned)__bfloat16_as_ushort(h0) | ((unsigned)__bfloat16_as_ushort(h1) << 16);
    lw = pk_bf16(f0 - r0, f1 - r1);
}

// qs[i][h] = sum_c W1[i, h*64+c] * as1[h,c]  (and qd with ad1)
__global__ void k_qprep(const float* __restrict__ W1, const float* __restrict__ as1,
                        const float* __restrict__ ad1, float* __restrict__ qs, float* __restrict__ qd) {
    int t = threadIdx.x;
    if (t < 32) {
        int i = t >> 1, h = t & 1;
        float s = 0.f, d = 0.f;
        for (int c = 0; c < 64; c++) {
            float w = W1[i * 128 + h * 64 + c];
            s = fmaf(w, as1[h * 64 + c], s);
            d = fmaf(w, ad1[h * 64 + c], d);
        }
        qs[i * 2 + h] = s; qd[i * 2 + h] = d;
    }
}

// al_s1[n,h] = x[n,:] . qs[:,h]
__global__ void k1n(const float* __restrict__ x, const float* __restrict__ qs,
                    const float* __restrict__ qd, float* __restrict__ al_s, float* __restrict__ al_d) {
    int n = blockIdx.x * 256 + threadIdx.x;
    if (n >= N_NODES) return;
    float s0 = 0.f, s1 = 0.f, d0 = 0.f, d1 = 0.f;
    #pragma unroll
    for (int i = 0; i < IN_DIM; i++) {
        float xv = x[n * IN_DIM + i];
        s0 = fmaf(xv, qs[i * 2 + 0], s0);
        s1 = fmaf(xv, qs[i * 2 + 1], s1);
        d0 = fmaf(xv, qd[i * 2 + 0], d0);
        d1 = fmaf(xv, qd[i * 2 + 1], d1);
    }
    al_s[n * 2 + 0] = s0; al_s[n * 2 + 1] = s1;
    al_d[n * 2 + 0] = d0; al_d[n * 2 + 1] = d1;
}

// CSR build
__global__ void k_hist(const int* __restrict__ dst, int* __restrict__ deg) {
    int e = blockIdx.x * blockDim.x + threadIdx.x;
    if (e < N_EDGES) atomicAdd(&deg[dst[e]], 1);
}

#define SCAN_B 256
__global__ void k_scan1(const int* __restrict__ deg, int* __restrict__ off, int* __restrict__ bsum) {
    __shared__ int sh[SCAN_B];
    int gid = blockIdx.x * SCAN_B + threadIdx.x;
    int v = (gid < N_NODES) ? deg[gid] : 0;
    sh[threadIdx.x] = v;
    __syncthreads();
    for (int o = 1; o < SCAN_B; o <<= 1) {
        int t = (threadIdx.x >= o) ? sh[threadIdx.x - o] : 0;
        __syncthreads();
        sh[threadIdx.x] += t;
        __syncthreads();
    }
    int incl = sh[threadIdx.x];
    if (gid < N_NODES) off[gid] = incl - v;
    if (threadIdx.x == SCAN_B - 1) bsum[blockIdx.x] = incl;
}
__global__ void k_scan2(int* __restrict__ bsum, int nblocks) {
    __shared__ int sh[SCAN_B];
    int v = (threadIdx.x < nblocks) ? bsum[threadIdx.x] : 0;
    sh[threadIdx.x] = v;
    __syncthreads();
    for (int o = 1; o < SCAN_B; o <<= 1) {
        int t = (threadIdx.x >= o) ? sh[threadIdx.x - o] : 0;
        __syncthreads();
        sh[threadIdx.x] += t;
        __syncthreads();
    }
    if (threadIdx.x < nblocks) bsum[threadIdx.x] = sh[threadIdx.x] - v;
}
__global__ void k_scan3(int* __restrict__ off, const int* __restrict__ bsum, int* __restrict__ cursor) {
    int gid = blockIdx.x * SCAN_B + threadIdx.x;
    if (gid < N_NODES) {
        int o = off[gid] + bsum[blockIdx.x];
        off[gid] = o;
        cursor[gid] = o;
    }
    if (gid == 0) off[N_NODES] = N_EDGES;
}
__global__ void k_scatter3(const int* __restrict__ src, const int* __restrict__ dst,
                           int* __restrict__ cursor, int* __restrict__ ssrc,
                           int* __restrict__ sdst, int* __restrict__ eid) {
    int e = blockIdx.x * blockDim.x + threadIdx.x;
    if (e < N_EDGES) {
        int d = dst[e];
        int pos = atomicAdd(&cursor[d], 1);
        ssrc[pos] = src[e];
        sdst[pos] = d;
        eid[pos] = e;
    }
}

// K3n: layer-1 aggregation in x-space, 4 independent online-softmax chains.
// 2 dsts per wave; 32 lanes per dst: head = (lane&31)>>4, ch = lane&15.
__global__ void k3n(const float* __restrict__ x, const float* __restrict__ als,
                    const float* __restrict__ ald, const int* __restrict__ off,
                    const int* __restrict__ ssrc, float* __restrict__ accx,
                    float* __restrict__ denb) {
    int wid = threadIdx.x >> 6, lane = threadIdx.x & 63;
    int half = lane >> 5, sub = lane & 31, head = sub >> 4, ch = sub & 15;
    int d = blockIdx.x * 8 + wid * 2 + half;
    if (d >= N_NODES) return;
    int beg = off[d], end = off[d + 1];
    float adv = ald[d * 2 + head];
    float m0 = lrelu(als[d * 2 + head] + adv), den0 = 1.f, a0 = x[d * IN_DIM + ch];
    float m1 = -1e30f, den1 = 0.f, a1 = 0.f;
    float m2v = -1e30f, den2 = 0.f, a2 = 0.f;
    float m3 = -1e30f, den3 = 0.f, a3 = 0.f;
    int i = beg;
    for (; i + 3 < end; i += 4) {
        int s0 = ssrc[i], s1 = ssrc[i + 1], s2 = ssrc[i + 2], s3 = ssrc[i + 3];
        float e0 = lrelu(als[s0 * 2 + head] + adv);
        float e1 = lrelu(als[s1 * 2 + head] + adv);
        float e2 = lrelu(als[s2 * 2 + head] + adv);
        float e3 = lrelu(als[s3 * 2 + head] + adv);
        float v0 = x[s0 * IN_DIM + ch], v1 = x[s1 * IN_DIM + ch];
        float v2 = x[s2 * IN_DIM + ch], v3 = x[s3 * IN_DIM + ch];
        sm_upd(m0, den0, a0, e0, v0);
        sm_upd(m1, den1, a1, e1, v1);
        sm_upd(m2v, den2, a2, e2, v2);
        sm_upd(m3, den3, a3, e3, v3);
    }
    for (; i < end; i++) {
        int s = ssrc[i];
        sm_upd(m0, den0, a0, lrelu(als[s * 2 + head] + adv), x[s * IN_DIM + ch]);
    }
    sm_merge(m0, den0, a0, m1, den1, a1);
    sm_merge(m2v, den2, a2, m3, den3, a3);
    sm_merge(m0, den0, a0, m2v, den2, a2);
    accx[d * 32 + sub] = a0;
    if ((sub & 15) == 0) denb[d * 2 + head] = den0;
}

// K4n: fused out1-expand (accx @ W1, /den, +b1, relu) then @ W2 -> h2, al_s2/al_d2.
__global__ __launch_bounds__(256) void k4n(
    const float* __restrict__ accx, const float* __restrict__ denb,
    const float* __restrict__ W1, const float* __restrict__ b1,
    const float* __restrict__ W2, const float* __restrict__ as2, const float* __restrict__ ad2,
    float* __restrict__ h2, float* __restrict__ al_s, float* __restrict__ al_d) {
    __shared__ float W1s[16 * 128];
    __shared__ float W2s[128 * 64];
    __shared__ float st[4][160];
    for (int t = threadIdx.x; t < 16 * 128; t += 256) W1s[t] = W1[t];
    for (int t = threadIdx.x; t < 128 * 64; t += 256) W2s[t] = W2[t];
    __syncthreads();
    int wid = threadIdx.x >> 6, lane = threadIdx.x & 63;
    int n = blockIdx.x * 4 + wid;
    if (n >= N_NODES) return;
    if (lane < 32) st[wid][lane] = accx[n * 32 + lane];
    float den0 = denb[n * 2], den1 = denb[n * 2 + 1];
    float ta = 0.f, tb = 0.f;
    #pragma unroll
    for (int i = 0; i < 16; i++) {
        ta = fmaf(st[wid][i],      W1s[i * 128 + lane],      ta);
        tb = fmaf(st[wid][16 + i], W1s[i * 128 + 64 + lane], tb);
    }
    ta = fmaxf(ta / den0 + b1[lane], 0.f);
    tb = fmaxf(tb / den1 + b1[64 + lane], 0.f);
    st[wid][32 + lane] = ta;
    st[wid][96 + lane] = tb;
    float acc = 0.f;
    #pragma unroll 8
    for (int k = 0; k < 128; k++) acc = fmaf(st[wid][32 + k], W2s[k * 64 + lane], acc);
    h2[n * 64 + lane] = acc;
    float ps = wave_reduce_sum(acc * as2[lane]);
    float pd = wave_reduce_sum(acc * ad2[lane]);
    if (lane == 0) { al_s[n] = ps; al_d[n] = pd; }
}

// K5a: layer-2 aggregation only. One dst per 64-thread block (wave-uniform scalar
// address path for ssrc/als), 4 independent online-softmax chains, no LDS.
__global__ __launch_bounds__(64) void k5a(
    const float* __restrict__ h2, const float* __restrict__ als, const float* __restrict__ ald,
    const float* __restrict__ b2, const int* __restrict__ off, const int* __restrict__ ssrc,
    float* __restrict__ out2) {
    int d = blockIdx.x;
    int lane = threadIdx.x;
    int beg = off[d], end = off[d + 1];
    float adv = ald[d];
    float m0 = lrelu(als[d] + adv), den0 = 1.f, a0 = h2[d * 64 + lane];
    float m1 = -1e30f, den1 = 0.f, a1 = 0.f;
    float m2v = -1e30f, den2 = 0.f, a2 = 0.f;
    float m3 = -1e30f, den3 = 0.f, a3 = 0.f;
    int i = beg;
    for (; i + 3 < end; i += 4) {
        int s0 = ssrc[i], s1 = ssrc[i + 1], s2 = ssrc[i + 2], s3 = ssrc[i + 3];
        float e0 = lrelu(als[s0] + adv), e1 = lrelu(als[s1] + adv);
        float e2 = lrelu(als[s2] + adv), e3 = lrelu(als[s3] + adv);
        float v0 = h2[s0 * 64 + lane], v1 = h2[s1 * 64 + lane];
        float v2 = h2[s2 * 64 + lane], v3 = h2[s3 * 64 + lane];
        sm_upd(m0, den0, a0, e0, v0);
        sm_upd(m1, den1, a1, e1, v1);
        sm_upd(m2v, den2, a2, e2, v2);
        sm_upd(m3, den3, a3, e3, v3);
    }
    for (; i < end; i++) {
        int s = ssrc[i];
        sm_upd(m0, den0, a0, lrelu(als[s] + adv), h2[s * 64 + lane]);
    }
    sm_merge(m0, den0, a0, m1, den1, a1);
    sm_merge(m2v, den2, a2, m3, den3, a3);
    sm_merge(m0, den0, a0, m2v, den2, a2);
    out2[d * 64 + lane] = fmaxf(a0 / den0 + b2[lane], 0.f);
}

// K5b: U = out2 @ mW1[0:64,:] + mb1, V = out2 @ mW1[64:128,:].
// NOTE: U may alias out2 (in-place per row) — data dependency via LDS protects ordering.
__global__ __launch_bounds__(256) void k5b(const float* out2, const float* __restrict__ mW1,
                                           const float* __restrict__ mb1,
                                           float* U, float* __restrict__ V) {
    __shared__ float Ws[128 * 64];
    __shared__ float o2s[4][64];
    for (int t = threadIdx.x; t < 128 * 64; t += 256) Ws[t] = mW1[t];
    __syncthreads();
    int wid = threadIdx.x >> 6, lane = threadIdx.x & 63;
    int n = blockIdx.x * 4 + wid;
    if (n >= N_NODES) return;
    o2s[wid][lane] = out2[n * 64 + lane];
    float au = mb1[lane], av = 0.f;
    #pragma unroll 8
    for (int k = 0; k < 64; k++) {
        float ov = o2s[wid][k];
        au = fmaf(ov, Ws[k * 64 + lane], au);
        av = fmaf(ov, Ws[(64 + k) * 64 + lane], av);
    }
    U[n * 64 + lane] = au;
    V[n * 64 + lane] = av;
}

// weight prep: W{2,3}t[b][t] = mW{2,3}[t*64+b] split into bf16 hi/lo tables
__global__ void k_wprep(const float* __restrict__ mW2, const float* __restrict__ mW3,
                        unsigned short* __restrict__ W2th, unsigned short* __restrict__ W2tl,
                        unsigned short* __restrict__ W3th, unsigned short* __restrict__ W3tl) {
    int b = blockIdx.x, t = threadIdx.x;
    float w2 = mW2[t * 64 + b];
    __hip_bfloat16 h2 = __float2bfloat16(w2);
    W2th[b * 64 + t] = __bfloat16_as_ushort(h2);
    W2tl[b * 64 + t] = __bfloat16_as_ushort(__float2bfloat16(w2 - __bfloat162float(h2)));
    float w3 = mW3[t * 64 + b];
    __hip_bfloat16 h3 = __float2bfloat16(w3);
    W3th[b * 64 + t] = __bfloat16_as_ushort(h3);
    W3tl[b * 64 + t] = __bfloat16_as_ushort(__float2bfloat16(w3 - __bfloat162float(h3)));
}

// K7d: edge MLP via MFMA, edges in CSR (dst-sorted) order for V locality; out via eid.
__global__ __launch_bounds__(256, 4) void k7d(
    const int* __restrict__ ssrc, const int* __restrict__ sdst, const int* __restrict__ eid,
    const float* __restrict__ Ub, const float* __restrict__ Vb,
    const unsigned short* __restrict__ W2th, const unsigned short* __restrict__ W2tl,
    const unsigned short* __restrict__ W3th, const unsigned short* __restrict__ W3tl,
    const float* __restrict__ mb2, const float* __restrict__ mb3,
    const float* __restrict__ mW4, const float* __restrict__ mb4,
    float* __restrict__ out)
{
    const int wid = threadIdx.x >> 6, lane = threadIdx.x & 63;
    const int ebase = blockIdx.x * 256 + wid * 64;
    const int l31 = lane & 31;
    const int h = lane >> 5;
    const int ksub = h * 8;

    int rfull = ssrc[ebase + lane];
    int cfull = sdst[ebase + lane];
    int efull = eid[ebase + lane];
    float b4v = mb4[0];

    #pragma unroll 1
    for (int nB = 0; nB < 2; nB++) {
        int rA = __shfl(rfull, nB * 32 + l31, 64);
        int cA = __shfl(cfull, nB * 32 + l31, 64);
        const float* urow = Ub + rA * 64 + ksub;
        const float* vrow = Vb + cA * 64 + ksub;

        f32x16 c2[2];
        #pragma unroll
        for (int mA = 0; mA < 2; mA++)
            #pragma unroll
            for (int r = 0; r < 16; r++)
                c2[mA][r] = mb2[mA * 32 + (r & 3) + 8 * (r >> 2) + 4 * h];

        #pragma unroll
        for (int kb = 0; kb < 4; kb++) {
            float4 u0 = *(const float4*)(urow + kb * 16);
            float4 u1 = *(const float4*)(urow + kb * 16 + 4);
            float4 v0 = *(const float4*)(vrow + kb * 16);
            float4 v1 = *(const float4*)(vrow + kb * 16 + 4);
            float z[8];
            z[0] = fmaxf(u0.x + v0.x, 0.f); z[1] = fmaxf(u0.y + v0.y, 0.f);
            z[2] = fmaxf(u0.z + v0.z, 0.f); z[3] = fmaxf(u0.w + v0.w, 0.f);
            z[4] = fmaxf(u1.x + v1.x, 0.f); z[5] = fmaxf(u1.y + v1.y, 0.f);
            z[6] = fmaxf(u1.z + v1.z, 0.f); z[7] = fmaxf(u1.w + v1.w, 0.f);
            U32x4S8 bh, bl;
            #pragma unroll
            for (int q = 0; q < 4; q++) hilo2(z[2 * q], z[2 * q + 1], bh.u[q], bl.u[q]);
            #pragma unroll
            for (int mA = 0; mA < 2; mA++) {
                const int wrow = (mA * 32 + l31) * 64 + kb * 16 + ksub;
                short8v ah = *(const short8v*)(W2th + wrow);
                short8v al = *(const short8v*)(W2tl + wrow);
                c2[mA] = __builtin_amdgcn_mfma_f32_32x32x16_bf16(ah, bh.s, c2[mA], 0, 0, 0);
                c2[mA] = __builtin_amdgcn_mfma_f32_32x32x16_bf16(al, bh.s, c2[mA], 0, 0, 0);
                c2[mA] = __builtin_amdgcn_mfma_f32_32x32x16_bf16(ah, bl.s, c2[mA], 0, 0, 0);
                c2[mA] = __builtin_amdgcn_mfma_f32_32x32x16_bf16(al, bl.s, c2[mA], 0, 0, 0);
            }
        }

        f32x16 c3[2];
        #pragma unroll
        for (int mA = 0; mA < 2; mA++)
            #pragma unroll
            for (int r = 0; r < 16; r++)
                c3[mA][r] = mb3[mA * 32 + (r & 3) + 8 * (r >> 2) + 4 * h];

        #pragma unroll
        for (int kbp = 0; kbp < 4; kbp++) {
            const int mAs = kbp >> 1, kbl = kbp & 1;
            float e[8];
            #pragma unroll
            for (int b = 0; b < 4; b++) {
                float u = fmaxf(c2[mAs][8 * kbl + b], 0.f);
                float v = fmaxf(c2[mAs][8 * kbl + 4 + b], 0.f);
                float su = __shfl_xor(u, 32, 64);
                float sv = __shfl_xor(v, 32, 64);
                e[b]     = h ? sv : u;
                e[4 + b] = h ? v : su;
            }
            U32x4S8 bh, bl;
            #pragma unroll
            for (int q = 0; q < 4; q++) hilo2(e[2 * q], e[2 * q + 1], bh.u[q], bl.u[q]);
            #pragma unroll
            for (int mA = 0; mA < 2; mA++) {
                const int wrow = (mA * 32 + l31) * 64 + kbp * 16 + ksub;
                short8v ah = *(const short8v*)(W3th + wrow);
                short8v al = *(const short8v*)(W3tl + wrow);
                c3[mA] = __builtin_amdgcn_mfma_f32_32x32x16_bf16(ah, bh.s, c3[mA], 0, 0, 0);
                c3[mA] = __builtin_amdgcn_mfma_f32_32x32x16_bf16(al, bh.s, c3[mA], 0, 0, 0);
                c3[mA] = __builtin_amdgcn_mfma_f32_32x32x16_bf16(ah, bl.s, c3[mA], 0, 0, 0);
                c3[mA] = __builtin_amdgcn_mfma_f32_32x32x16_bf16(al, bl.s, c3[mA], 0, 0, 0);
            }
        }

        float p = 0.f;
        #pragma unroll
        for (int mA = 0; mA < 2; mA++)
            #pragma unroll
            for (int r = 0; r < 16; r++)
                p = fmaf(fmaxf(c3[mA][r], 0.f), mW4[mA * 32 + (r & 3) + 8 * (r >> 2) + 4 * h], p);
        p += __shfl_xor(p, 32, 64);
        int oidx = __shfl(efull, nB * 32 + lane, 64);
        if (lane < 32) out[oidx] = p + b4v;
    }
}

extern "C" void kernel_launch(void* const* d_in, const int* in_sizes, int n_in,
                              void* d_out, int out_size, void* d_ws, size_t ws_size,
                              hipStream_t stream) {
    const float* x   = (const float*)d_in[0];
    const int*   ei  = (const int*)d_in[1];
    const float* W1  = (const float*)d_in[2];
    const float* as1 = (const float*)d_in[3];
    const float* ad1 = (const float*)d_in[4];
    const float* b1  = (const float*)d_in[5];
    const float* W2  = (const float*)d_in[6];
    const float* as2 = (const float*)d_in[7];
    const float* ad2 = (const float*)d_in[8];
    const float* b2  = (const float*)d_in[9];
    const float* mW1 = (const float*)d_in[10];
    const float* mb1 = (const float*)d_in[11];
    const float* mW2 = (const float*)d_in[12];
    const float* mb2 = (const float*)d_in[13];
    const float* mW3 = (const float*)d_in[14];
    const float* mb3 = (const float*)d_in[15];
    const float* mW4 = (const float*)d_in[16];
    const float* mb4 = (const float*)d_in[17];
    float* out = (float*)d_out;
    const int* row = ei;             // src
    const int* col = ei + N_EDGES;   // dst

    char* w = (char*)d_ws;
    float* U     = (float*)w;                         // 12.8 MB, live k5b->k7
    float* V     = (float*)(w + 12800000);            // 12.8 MB, live k5b->k7
    float* h2    = (float*)(w + 25600000);            // 12.8 MB, live k4->k5a
    int*   ssrc  = (int*)(w + 38400000);              // 6.4 MB
    int*   sdst  = (int*)(w + 44800000);              // 6.4 MB
    int*   eid   = (int*)(w + 51200000);              // 6.4 MB
    int*   deg   = (int*)(w + 57600000);              // 0.2 MB
    int*   offp  = (int*)(w + 57800000);              // 0.2 MB + 4
    int*   cursor= (int*)(w + 58000064);              // 0.2 MB
    float* al_s2 = (float*)(w + 58200064);
    float* al_d2 = (float*)(w + 58400064);
    int*   bsum  = (int*)(w + 58600064);              // 1 KB
    float* qs    = (float*)(w + 58601088);            // 128 B
    float* qd    = (float*)(w + 58601216);            // 128 B
    unsigned short* W2th = (unsigned short*)(w + 58601344);
    unsigned short* W2tl = W2th + 4096;
    unsigned short* W3th = W2th + 8192;
    unsigned short* W3tl = W2th + 12288;
    // overlays inside U region (all dead before k5b writes U):
    float* accx  = U;                                 // 6.4 MB, live k3->k4
    float* denb  = (float*)(w + 6400000);             // 0.4 MB, live k3->k4
    float* al_s1 = (float*)(w + 6800000);             // 0.4 MB, live k1->k3
    float* al_d1 = (float*)(w + 7200000);             // 0.4 MB, live k1->k3
    float* out2  = U;                                 // 12.8 MB, live k5a->k5b (in-place to U)

    hipMemsetAsync(deg, 0, N_NODES * sizeof(int), stream);
    k_qprep<<<1, 64, 0, stream>>>(W1, as1, ad1, qs, qd);
    k_wprep<<<64, 64, 0, stream>>>(mW2, mW3, W2th, W2tl, W3th, W3tl);
    k1n<<<(N_NODES + 255) / 256, 256, 0, stream>>>(x, qs, qd, al_s1, al_d1);
    k_hist<<<(N_EDGES + 255) / 256, 256, 0, stream>>>(col, deg);
    k_scan1<<<(N_NODES + SCAN_B - 1) / SCAN_B, SCAN_B, 0, stream>>>(deg, offp, bsum);
    k_scan2<<<1, SCAN_B, 0, stream>>>(bsum, (N_NODES + SCAN_B - 1) / SCAN_B);
    k_scan3<<<(N_NODES + SCAN_B - 1) / SCAN_B, SCAN_B, 0, stream>>>(offp, bsum, cursor);
    k_scatter3<<<(N_EDGES + 255) / 256, 256, 0, stream>>>(row, col, cursor, ssrc, sdst, eid);
    k3n<<<N_NODES / 8, 256, 0, stream>>>(x, al_s1, al_d1, offp, ssrc, accx, denb);
    k4n<<<N_NODES / 4, 256, 0, stream>>>(accx, denb, W1, b1, W2, as2, ad2, h2, al_s2, al_d2);
    k5a<<<N_NODES, 64, 0, stream>>>(h2, al_s2, al_d2, b2, offp, ssrc, out2);
    k5b<<<N_NODES / 4, 256, 0, stream>>>(out2, mW1, mb1, U, V);
    k7d<<<N_EDGES / 256, 256, 0, stream>>>(ssrc, sdst, eid, U, V,
                                           W2th, W2tl, W3th, W3tl,
                                           mb2, mb3, mW4, mb4, out);
}

// Round 6
// 684.251 us; speedup vs baseline: 1.5622x; 1.5622x over previous
//
#include <hip/hip_runtime.h>
#include <hip/hip_bf16.h>
#include <math.h>

#define N_NODES 50000
#define N_EDGES 1600000
#define IN_DIM 16
#define HID 64

typedef __attribute__((ext_vector_type(8))) short short8v;
typedef __attribute__((ext_vector_type(16))) float f32x16;

union U32x4S8 { unsigned u[4]; short8v s; };

__device__ __forceinline__ float lrelu(float v) { return v > 0.f ? v : 0.2f * v; }

__device__ __forceinline__ float wave_reduce_sum(float v) {
    #pragma unroll
    for (int off = 32; off > 0; off >>= 1) v += __shfl_down(v, off, 64);
    return v;
}

// online-softmax state update: state (m, den, acc) absorbs element (e, v)
__device__ __forceinline__ void sm_upd(float& m, float& den, float& acc, float e, float v) {
    float n = fmaxf(m, e);
    float f = __expf(m - n), w = __expf(e - n);
    den = den * f + w;
    acc = acc * f + w * v;
    m = n;
}
// associative merge of two online-softmax states
__device__ __forceinline__ void sm_merge(float& m, float& den, float& acc,
                                         float m2, float den2, float acc2) {
    float mm = fmaxf(m, m2);
    float f1 = __expf(m - mm), f2 = __expf(m2 - mm);
    den = den * f1 + den2 * f2;
    acc = acc * f1 + acc2 * f2;
    m = mm;
}

__device__ __forceinline__ unsigned pk_bf16(float a, float b) {
    unsigned ua = (unsigned)__bfloat16_as_ushort(__float2bfloat16(a));
    unsigned ub = (unsigned)__bfloat16_as_ushort(__float2bfloat16(b));
    return ua | (ub << 16);
}

__device__ __forceinline__ void hilo2(float f0, float f1, unsigned& hw, unsigned& lw) {
    __hip_bfloat16 h0 = __float2bfloat16(f0), h1 = __float2bfloat16(f1);
    float r0 = __bfloat162float(h0), r1 = __bfloat162float(h1);
    hw = (unsigned)__bfloat16_as_ushort(h0) | ((unsigned)__bfloat16_as_ushort(h1) << 16);
    lw = pk_bf16(f0 - r0, f1 - r1);
}

// qs[i][h] = sum_c W1[i, h*64+c] * as1[h,c]  (and qd with ad1)
__global__ void k_qprep(const float* __restrict__ W1, const float* __restrict__ as1,
                        const float* __restrict__ ad1, float* __restrict__ qs, float* __restrict__ qd) {
    int t = threadIdx.x;
    if (t < 32) {
        int i = t >> 1, h = t & 1;
        float s = 0.f, d = 0.f;
        for (int c = 0; c < 64; c++) {
            float w = W1[i * 128 + h * 64 + c];
            s = fmaf(w, as1[h * 64 + c], s);
            d = fmaf(w, ad1[h * 64 + c], d);
        }
        qs[i * 2 + h] = s; qd[i * 2 + h] = d;
    }
}

// al_s1[n,h] = x[n,:] . qs[:,h]
__global__ void k1n(const float* __restrict__ x, const float* __restrict__ qs,
                    const float* __restrict__ qd, float* __restrict__ al_s, float* __restrict__ al_d) {
    int n = blockIdx.x * 256 + threadIdx.x;
    if (n >= N_NODES) return;
    float s0 = 0.f, s1 = 0.f, d0 = 0.f, d1 = 0.f;
    #pragma unroll
    for (int i = 0; i < IN_DIM; i++) {
        float xv = x[n * IN_DIM + i];
        s0 = fmaf(xv, qs[i * 2 + 0], s0);
        s1 = fmaf(xv, qs[i * 2 + 1], s1);
        d0 = fmaf(xv, qd[i * 2 + 0], d0);
        d1 = fmaf(xv, qd[i * 2 + 1], d1);
    }
    al_s[n * 2 + 0] = s0; al_s[n * 2 + 1] = s1;
    al_d[n * 2 + 0] = d0; al_d[n * 2 + 1] = d1;
}

// CSR build
__global__ void k_hist(const int* __restrict__ dst, int* __restrict__ deg) {
    int e = blockIdx.x * blockDim.x + threadIdx.x;
    if (e < N_EDGES) atomicAdd(&deg[dst[e]], 1);
}

#define SCAN_B 256
__global__ void k_scan1(const int* __restrict__ deg, int* __restrict__ off, int* __restrict__ bsum) {
    __shared__ int sh[SCAN_B];
    int gid = blockIdx.x * SCAN_B + threadIdx.x;
    int v = (gid < N_NODES) ? deg[gid] : 0;
    sh[threadIdx.x] = v;
    __syncthreads();
    for (int o = 1; o < SCAN_B; o <<= 1) {
        int t = (threadIdx.x >= o) ? sh[threadIdx.x - o] : 0;
        __syncthreads();
        sh[threadIdx.x] += t;
        __syncthreads();
    }
    int incl = sh[threadIdx.x];
    if (gid < N_NODES) off[gid] = incl - v;
    if (threadIdx.x == SCAN_B - 1) bsum[blockIdx.x] = incl;
}
__global__ void k_scan2(int* __restrict__ bsum, int nblocks) {
    __shared__ int sh[SCAN_B];
    int v = (threadIdx.x < nblocks) ? bsum[threadIdx.x] : 0;
    sh[threadIdx.x] = v;
    __syncthreads();
    for (int o = 1; o < SCAN_B; o <<= 1) {
        int t = (threadIdx.x >= o) ? sh[threadIdx.x - o] : 0;
        __syncthreads();
        sh[threadIdx.x] += t;
        __syncthreads();
    }
    if (threadIdx.x < nblocks) bsum[threadIdx.x] = sh[threadIdx.x] - v;
}
__global__ void k_scan3(int* __restrict__ off, const int* __restrict__ bsum, int* __restrict__ cursor) {
    int gid = blockIdx.x * SCAN_B + threadIdx.x;
    if (gid < N_NODES) {
        int o = off[gid] + bsum[blockIdx.x];
        off[gid] = o;
        cursor[gid] = o;
    }
    if (gid == 0) off[N_NODES] = N_EDGES;
}
__global__ void k_scatter3(const int* __restrict__ src, const int* __restrict__ dst,
                           int* __restrict__ cursor, int* __restrict__ ssrc,
                           int* __restrict__ sdst, int* __restrict__ eid) {
    int e = blockIdx.x * blockDim.x + threadIdx.x;
    if (e < N_EDGES) {
        int d = dst[e];
        int pos = atomicAdd(&cursor[d], 1);
        ssrc[pos] = src[e];
        sdst[pos] = d;
        eid[pos] = e;
    }
}

// K3n: layer-1 aggregation in x-space, 4 independent online-softmax chains.
__global__ void k3n(const float* __restrict__ x, const float* __restrict__ als,
                    const float* __restrict__ ald, const int* __restrict__ off,
                    const int* __restrict__ ssrc, float* __restrict__ accx,
                    float* __restrict__ denb) {
    int wid = threadIdx.x >> 6, lane = threadIdx.x & 63;
    int half = lane >> 5, sub = lane & 31, head = sub >> 4, ch = sub & 15;
    int d = blockIdx.x * 8 + wid * 2 + half;
    if (d >= N_NODES) return;
    int beg = off[d], end = off[d + 1];
    float adv = ald[d * 2 + head];
    float m0 = lrelu(als[d * 2 + head] + adv), den0 = 1.f, a0 = x[d * IN_DIM + ch];
    float m1 = -1e30f, den1 = 0.f, a1 = 0.f;
    float m2v = -1e30f, den2 = 0.f, a2 = 0.f;
    float m3 = -1e30f, den3 = 0.f, a3 = 0.f;
    int i = beg;
    for (; i + 3 < end; i += 4) {
        int s0 = ssrc[i], s1 = ssrc[i + 1], s2 = ssrc[i + 2], s3 = ssrc[i + 3];
        float e0 = lrelu(als[s0 * 2 + head] + adv);
        float e1 = lrelu(als[s1 * 2 + head] + adv);
        float e2 = lrelu(als[s2 * 2 + head] + adv);
        float e3 = lrelu(als[s3 * 2 + head] + adv);
        float v0 = x[s0 * IN_DIM + ch], v1 = x[s1 * IN_DIM + ch];
        float v2 = x[s2 * IN_DIM + ch], v3 = x[s3 * IN_DIM + ch];
        sm_upd(m0, den0, a0, e0, v0);
        sm_upd(m1, den1, a1, e1, v1);
        sm_upd(m2v, den2, a2, e2, v2);
        sm_upd(m3, den3, a3, e3, v3);
    }
    for (; i < end; i++) {
        int s = ssrc[i];
        sm_upd(m0, den0, a0, lrelu(als[s * 2 + head] + adv), x[s * IN_DIM + ch]);
    }
    sm_merge(m0, den0, a0, m1, den1, a1);
    sm_merge(m2v, den2, a2, m3, den3, a3);
    sm_merge(m0, den0, a0, m2v, den2, a2);
    accx[d * 32 + sub] = a0;
    if ((sub & 15) == 0) denb[d * 2 + head] = den0;
}

// K4n: fused out1-expand (accx @ W1, /den, +b1, relu) then @ W2 -> h2, al_s2/al_d2.
__global__ __launch_bounds__(256) void k4n(
    const float* __restrict__ accx, const float* __restrict__ denb,
    const float* __restrict__ W1, const float* __restrict__ b1,
    const float* __restrict__ W2, const float* __restrict__ as2, const float* __restrict__ ad2,
    float* __restrict__ h2, float* __restrict__ al_s, float* __restrict__ al_d) {
    __shared__ float W1s[16 * 128];
    __shared__ float W2s[128 * 64];
    __shared__ float st[4][160];
    for (int t = threadIdx.x; t < 16 * 128; t += 256) W1s[t] = W1[t];
    for (int t = threadIdx.x; t < 128 * 64; t += 256) W2s[t] = W2[t];
    __syncthreads();
    int wid = threadIdx.x >> 6, lane = threadIdx.x & 63;
    int n = blockIdx.x * 4 + wid;
    if (n >= N_NODES) return;
    if (lane < 32) st[wid][lane] = accx[n * 32 + lane];
    float den0 = denb[n * 2], den1 = denb[n * 2 + 1];
    float ta = 0.f, tb = 0.f;
    #pragma unroll
    for (int i = 0; i < 16; i++) {
        ta = fmaf(st[wid][i],      W1s[i * 128 + lane],      ta);
        tb = fmaf(st[wid][16 + i], W1s[i * 128 + 64 + lane], tb);
    }
    ta = fmaxf(ta / den0 + b1[lane], 0.f);
    tb = fmaxf(tb / den1 + b1[64 + lane], 0.f);
    st[wid][32 + lane] = ta;
    st[wid][96 + lane] = tb;
    float acc = 0.f;
    #pragma unroll 8
    for (int k = 0; k < 128; k++) acc = fmaf(st[wid][32 + k], W2s[k * 64 + lane], acc);
    h2[n * 64 + lane] = acc;
    float ps = wave_reduce_sum(acc * as2[lane]);
    float pd = wave_reduce_sum(acc * ad2[lane]);
    if (lane == 0) { al_s[n] = ps; al_d[n] = pd; }
}

// K5a: layer-2 aggregation only. One dst per 64-thread block, 4 chains, no LDS.
__global__ __launch_bounds__(64) void k5a(
    const float* __restrict__ h2, const float* __restrict__ als, const float* __restrict__ ald,
    const float* __restrict__ b2, const int* __restrict__ off, const int* __restrict__ ssrc,
    float* __restrict__ out2) {
    int d = blockIdx.x;
    int lane = threadIdx.x;
    int beg = off[d], end = off[d + 1];
    float adv = ald[d];
    float m0 = lrelu(als[d] + adv), den0 = 1.f, a0 = h2[d * 64 + lane];
    float m1 = -1e30f, den1 = 0.f, a1 = 0.f;
    float m2v = -1e30f, den2 = 0.f, a2 = 0.f;
    float m3 = -1e30f, den3 = 0.f, a3 = 0.f;
    int i = beg;
    for (; i + 3 < end; i += 4) {
        int s0 = ssrc[i], s1 = ssrc[i + 1], s2 = ssrc[i + 2], s3 = ssrc[i + 3];
        float e0 = lrelu(als[s0] + adv), e1 = lrelu(als[s1] + adv);
        float e2 = lrelu(als[s2] + adv), e3 = lrelu(als[s3] + adv);
        float v0 = h2[s0 * 64 + lane], v1 = h2[s1 * 64 + lane];
        float v2 = h2[s2 * 64 + lane], v3 = h2[s3 * 64 + lane];
        sm_upd(m0, den0, a0, e0, v0);
        sm_upd(m1, den1, a1, e1, v1);
        sm_upd(m2v, den2, a2, e2, v2);
        sm_upd(m3, den3, a3, e3, v3);
    }
    for (; i < end; i++) {
        int s = ssrc[i];
        sm_upd(m0, den0, a0, lrelu(als[s] + adv), h2[s * 64 + lane]);
    }
    sm_merge(m0, den0, a0, m1, den1, a1);
    sm_merge(m2v, den2, a2, m3, den3, a3);
    sm_merge(m0, den0, a0, m2v, den2, a2);
    out2[d * 64 + lane] = fmaxf(a0 / den0 + b2[lane], 0.f);
}

// K5b: U = out2 @ mW1[0:64,:] + mb1, V = out2 @ mW1[64:128,:].
__global__ __launch_bounds__(256) void k5b(const float* out2, const float* __restrict__ mW1,
                                           const float* __restrict__ mb1,
                                           float* U, float* __restrict__ V) {
    __shared__ float Ws[128 * 64];
    __shared__ float o2s[4][64];
    for (int t = threadIdx.x; t < 128 * 64; t += 256) Ws[t] = mW1[t];
    __syncthreads();
    int wid = threadIdx.x >> 6, lane = threadIdx.x & 63;
    int n = blockIdx.x * 4 + wid;
    if (n >= N_NODES) return;
    o2s[wid][lane] = out2[n * 64 + lane];
    float au = mb1[lane], av = 0.f;
    #pragma unroll 8
    for (int k = 0; k < 64; k++) {
        float ov = o2s[wid][k];
        au = fmaf(ov, Ws[k * 64 + lane], au);
        av = fmaf(ov, Ws[(64 + k) * 64 + lane], av);
    }
    U[n * 64 + lane] = au;
    V[n * 64 + lane] = av;
}

// weight prep: W{2,3}t[b][t] = mW{2,3}[t*64+b] split into bf16 hi/lo tables
__global__ void k_wprep(const float* __restrict__ mW2, const float* __restrict__ mW3,
                        unsigned short* __restrict__ W2th, unsigned short* __restrict__ W2tl,
                        unsigned short* __restrict__ W3th, unsigned short* __restrict__ W3tl) {
    int b = blockIdx.x, t = threadIdx.x;
    float w2 = mW2[t * 64 + b];
    __hip_bfloat16 h2 = __float2bfloat16(w2);
    W2th[b * 64 + t] = __bfloat16_as_ushort(h2);
    W2tl[b * 64 + t] = __bfloat16_as_ushort(__float2bfloat16(w2 - __bfloat162float(h2)));
    float w3 = mW3[t * 64 + b];
    __hip_bfloat16 h3 = __float2bfloat16(w3);
    W3th[b * 64 + t] = __bfloat16_as_ushort(h3);
    W3tl[b * 64 + t] = __bfloat16_as_ushort(__float2bfloat16(w3 - __bfloat162float(h3)));
}

// K7d: edge MLP via MFMA, edges in CSR (dst-sorted) order for V locality; out via eid.
// NOTE: no min-waves launch bound — forcing 4 waves/SIMD spills (R5: VGPR 64, 2.7 GB scratch traffic).
__global__ __launch_bounds__(256) void k7d(
    const int* __restrict__ ssrc, const int* __restrict__ sdst, const int* __restrict__ eid,
    const float* __restrict__ Ub, const float* __restrict__ Vb,
    const unsigned short* __restrict__ W2th, const unsigned short* __restrict__ W2tl,
    const unsigned short* __restrict__ W3th, const unsigned short* __restrict__ W3tl,
    const float* __restrict__ mb2, const float* __restrict__ mb3,
    const float* __restrict__ mW4, const float* __restrict__ mb4,
    float* __restrict__ out)
{
    const int wid = threadIdx.x >> 6, lane = threadIdx.x & 63;
    const int ebase = blockIdx.x * 256 + wid * 64;
    const int l31 = lane & 31;
    const int h = lane >> 5;
    const int ksub = h * 8;

    int rfull = ssrc[ebase + lane];
    int cfull = sdst[ebase + lane];
    int efull = eid[ebase + lane];
    float b4v = mb4[0];

    #pragma unroll 1
    for (int nB = 0; nB < 2; nB++) {
        int rA = __shfl(rfull, nB * 32 + l31, 64);
        int cA = __shfl(cfull, nB * 32 + l31, 64);
        const float* urow = Ub + rA * 64 + ksub;
        const float* vrow = Vb + cA * 64 + ksub;

        f32x16 c2[2];
        #pragma unroll
        for (int mA = 0; mA < 2; mA++)
            #pragma unroll
            for (int r = 0; r < 16; r++)
                c2[mA][r] = mb2[mA * 32 + (r & 3) + 8 * (r >> 2) + 4 * h];

        #pragma unroll
        for (int kb = 0; kb < 4; kb++) {
            float4 u0 = *(const float4*)(urow + kb * 16);
            float4 u1 = *(const float4*)(urow + kb * 16 + 4);
            float4 v0 = *(const float4*)(vrow + kb * 16);
            float4 v1 = *(const float4*)(vrow + kb * 16 + 4);
            float z[8];
            z[0] = fmaxf(u0.x + v0.x, 0.f); z[1] = fmaxf(u0.y + v0.y, 0.f);
            z[2] = fmaxf(u0.z + v0.z, 0.f); z[3] = fmaxf(u0.w + v0.w, 0.f);
            z[4] = fmaxf(u1.x + v1.x, 0.f); z[5] = fmaxf(u1.y + v1.y, 0.f);
            z[6] = fmaxf(u1.z + v1.z, 0.f); z[7] = fmaxf(u1.w + v1.w, 0.f);
            U32x4S8 bh, bl;
            #pragma unroll
            for (int q = 0; q < 4; q++) hilo2(z[2 * q], z[2 * q + 1], bh.u[q], bl.u[q]);
            #pragma unroll
            for (int mA = 0; mA < 2; mA++) {
                const int wrow = (mA * 32 + l31) * 64 + kb * 16 + ksub;
                short8v ah = *(const short8v*)(W2th + wrow);
                short8v al = *(const short8v*)(W2tl + wrow);
                c2[mA] = __builtin_amdgcn_mfma_f32_32x32x16_bf16(ah, bh.s, c2[mA], 0, 0, 0);
                c2[mA] = __builtin_amdgcn_mfma_f32_32x32x16_bf16(al, bh.s, c2[mA], 0, 0, 0);
                c2[mA] = __builtin_amdgcn_mfma_f32_32x32x16_bf16(ah, bl.s, c2[mA], 0, 0, 0);
                c2[mA] = __builtin_amdgcn_mfma_f32_32x32x16_bf16(al, bl.s, c2[mA], 0, 0, 0);
            }
        }

        f32x16 c3[2];
        #pragma unroll
        for (int mA = 0; mA < 2; mA++)
            #pragma unroll
            for (int r = 0; r < 16; r++)
                c3[mA][r] = mb3[mA * 32 + (r & 3) + 8 * (r >> 2) + 4 * h];

        #pragma unroll
        for (int kbp = 0; kbp < 4; kbp++) {
            const int mAs = kbp >> 1, kbl = kbp & 1;
            float e[8];
            #pragma unroll
            for (int b = 0; b < 4; b++) {
                float u = fmaxf(c2[mAs][8 * kbl + b], 0.f);
                float v = fmaxf(c2[mAs][8 * kbl + 4 + b], 0.f);
                float su = __shfl_xor(u, 32, 64);
                float sv = __shfl_xor(v, 32, 64);
                e[b]     = h ? sv : u;
                e[4 + b] = h ? v : su;
            }
            U32x4S8 bh, bl;
            #pragma unroll
            for (int q = 0; q < 4; q++) hilo2(e[2 * q], e[2 * q + 1], bh.u[q], bl.u[q]);
            #pragma unroll
            for (int mA = 0; mA < 2; mA++) {
                const int wrow = (mA * 32 + l31) * 64 + kbp * 16 + ksub;
                short8v ah = *(const short8v*)(W3th + wrow);
                short8v al = *(const short8v*)(W3tl + wrow);
                c3[mA] = __builtin_amdgcn_mfma_f32_32x32x16_bf16(ah, bh.s, c3[mA], 0, 0, 0);
                c3[mA] = __builtin_amdgcn_mfma_f32_32x32x16_bf16(al, bh.s, c3[mA], 0, 0, 0);
                c3[mA] = __builtin_amdgcn_mfma_f32_32x32x16_bf16(ah, bl.s, c3[mA], 0, 0, 0);
                c3[mA] = __builtin_amdgcn_mfma_f32_32x32x16_bf16(al, bl.s, c3[mA], 0, 0, 0);
            }
        }

        float p = 0.f;
        #pragma unroll
        for (int mA = 0; mA < 2; mA++)
            #pragma unroll
            for (int r = 0; r < 16; r++)
                p = fmaf(fmaxf(c3[mA][r], 0.f), mW4[mA * 32 + (r & 3) + 8 * (r >> 2) + 4 * h], p);
        p += __shfl_xor(p, 32, 64);
        int oidx = __shfl(efull, nB * 32 + lane, 64);
        if (lane < 32) out[oidx] = p + b4v;
    }
}

extern "C" void kernel_launch(void* const* d_in, const int* in_sizes, int n_in,
                              void* d_out, int out_size, void* d_ws, size_t ws_size,
                              hipStream_t stream) {
    const float* x   = (const float*)d_in[0];
    const int*   ei  = (const int*)d_in[1];
    const float* W1  = (const float*)d_in[2];
    const float* as1 = (const float*)d_in[3];
    const float* ad1 = (const float*)d_in[4];
    const float* b1  = (const float*)d_in[5];
    const float* W2  = (const float*)d_in[6];
    const float* as2 = (const float*)d_in[7];
    const float* ad2 = (const float*)d_in[8];
    const float* b2  = (const float*)d_in[9];
    const float* mW1 = (const float*)d_in[10];
    const float* mb1 = (const float*)d_in[11];
    const float* mW2 = (const float*)d_in[12];
    const float* mb2 = (const float*)d_in[13];
    const float* mW3 = (const float*)d_in[14];
    const float* mb3 = (const float*)d_in[15];
    const float* mW4 = (const float*)d_in[16];
    const float* mb4 = (const float*)d_in[17];
    float* out = (float*)d_out;
    const int* row = ei;             // src
    const int* col = ei + N_EDGES;   // dst

    char* w = (char*)d_ws;
    float* U     = (float*)w;                         // 12.8 MB, live k5b->k7
    float* V     = (float*)(w + 12800000);            // 12.8 MB, live k5b->k7
    float* h2    = (float*)(w + 25600000);            // 12.8 MB, live k4->k5a
    int*   ssrc  = (int*)(w + 38400000);              // 6.4 MB
    int*   sdst  = (int*)(w + 44800000);              // 6.4 MB
    int*   eid   = (int*)(w + 51200000);              // 6.4 MB
    int*   deg   = (int*)(w + 57600000);              // 0.2 MB
    int*   offp  = (int*)(w + 57800000);              // 0.2 MB + 4
    int*   cursor= (int*)(w + 58000064);              // 0.2 MB
    float* al_s2 = (float*)(w + 58200064);
    float* al_d2 = (float*)(w + 58400064);
    int*   bsum  = (int*)(w + 58600064);              // 1 KB
    float* qs    = (float*)(w + 58601088);            // 128 B
    float* qd    = (float*)(w + 58601216);            // 128 B
    unsigned short* W2th = (unsigned short*)(w + 58601344);
    unsigned short* W2tl = W2th + 4096;
    unsigned short* W3th = W2th + 8192;
    unsigned short* W3tl = W2th + 12288;
    // overlays inside U region (all dead before k5b writes U):
    float* accx  = U;                                 // 6.4 MB, live k3->k4
    float* denb  = (float*)(w + 6400000);             // 0.4 MB, live k3->k4
    float* al_s1 = (float*)(w + 6800000);             // 0.4 MB, live k1->k3
    float* al_d1 = (float*)(w + 7200000);             // 0.4 MB, live k1->k3
    float* out2  = U;                                 // 12.8 MB, live k5a->k5b (in-place to U)

    hipMemsetAsync(deg, 0, N_NODES * sizeof(int), stream);
    k_qprep<<<1, 64, 0, stream>>>(W1, as1, ad1, qs, qd);
    k_wprep<<<64, 64, 0, stream>>>(mW2, mW3, W2th, W2tl, W3th, W3tl);
    k1n<<<(N_NODES + 255) / 256, 256, 0, stream>>>(x, qs, qd, al_s1, al_d1);
    k_hist<<<(N_EDGES + 255) / 256, 256, 0, stream>>>(col, deg);
    k_scan1<<<(N_NODES + SCAN_B - 1) / SCAN_B, SCAN_B, 0, stream>>>(deg, offp, bsum);
    k_scan2<<<1, SCAN_B, 0, stream>>>(bsum, (N_NODES + SCAN_B - 1) / SCAN_B);
    k_scan3<<<(N_NODES + SCAN_B - 1) / SCAN_B, SCAN_B, 0, stream>>>(offp, bsum, cursor);
    k_scatter3<<<(N_EDGES + 255) / 256, 256, 0, stream>>>(row, col, cursor, ssrc, sdst, eid);
    k3n<<<N_NODES / 8, 256, 0, stream>>>(x, al_s1, al_d1, offp, ssrc, accx, denb);
    k4n<<<N_NODES / 4, 256, 0, stream>>>(accx, denb, W1, b1, W2, as2, ad2, h2, al_s2, al_d2);
    k5a<<<N_NODES, 64, 0, stream>>>(h2, al_s2, al_d2, b2, offp, ssrc, out2);
    k5b<<<N_NODES / 4, 256, 0, stream>>>(out2, mW1, mb1, U, V);
    k7d<<<N_EDGES / 256, 256, 0, stream>>>(ssrc, sdst, eid, U, V,
                                           W2th, W2tl, W3th, W3tl,
                                           mb2, mb3, mW4, mb4, out);
}